// Round 9
// baseline (169.987 us; speedup 1.0000x reference)
//
#include <hip/hip_runtime.h>
#include <cfloat>
#include <climits>

#define B_DIM 16
#define C_DIM 64
#define N_DIM 2048
#define O_DIM 64
#define K_NN  3

typedef __attribute__((ext_vector_type(8))) short bf16x8;
typedef __attribute__((ext_vector_type(4))) float floatx4;

__device__ __forceinline__ unsigned short f32_to_bf16_rne(float f) {
  unsigned int u = __float_as_uint(f);
  return (unsigned short)((u + 0x7fffu + ((u >> 16) & 1u)) >> 16);
}
__device__ __forceinline__ float bf16_to_f32(unsigned short h) {
  return __uint_as_float(((unsigned int)h) << 16);
}

// Branchless fp32 top-3 insert (membership only; exact re-rank later).
// Top-3 per stream is sufficient: only the global #1,#2 can displace #3.
__device__ __forceinline__ void ins3(float key, int jv, float* k, int* j) {
  bool c2 = key < k[2], c1 = key < k[1], c0 = key < k[0];
  k[2] = c1 ? k[1] : (c2 ? key : k[2]);
  j[2] = c1 ? j[1] : (c2 ? jv  : j[2]);
  k[1] = c0 ? k[0] : (c1 ? key : k[1]);
  j[1] = c0 ? j[0] : (c1 ? jv  : j[1]);
  k[0] = c0 ? key : k[0];
  j[0] = c0 ? jv  : j[0];
}

// split 8 fp32 -> bf16 hi + bf16 lo fragments
__device__ __forceinline__ void split8(const float* v, bf16x8* h8, bf16x8* l8) {
  unsigned short h[8], l[8];
  #pragma unroll
  for (int e = 0; e < 8; ++e) {
    h[e] = f32_to_bf16_rne(v[e]);
    l[e] = f32_to_bf16_rne(v[e] - bf16_to_f32(h[e]));
  }
  *h8 = *(bf16x8*)h;
  *l8 = *(bf16x8*)l;
}

// ---- kernel 1: x -> xT fp32 [B][N][C] + fp32 norms. Blocks >= 512: W^T ----
__global__ __launch_bounds__(256) void prep_kernel(
    const float* __restrict__ x, float* __restrict__ xT,
    float* __restrict__ nf,
    const float* __restrict__ W, float* __restrict__ Wt) {
  int bid = blockIdx.x;
  int t = threadIdx.x;
  if (bid >= 512) {                  // W transpose: 48 blocks
    int t2 = (bid - 512) * 256 + t;  // 12288 = O * C * K
    int o  = t2 / (C_DIM * K_NN);
    int ck = t2 - o * (C_DIM * K_NN);
    Wt[ck * O_DIM + o] = W[t2];
    return;
  }
  __shared__ __align__(16) float xs[C_DIM][68];
  int b  = bid >> 5;
  int n0 = (bid & 31) * 64;
  const float* xb = x + (size_t)b * C_DIM * N_DIM;
  #pragma unroll
  for (int r = 0; r < 4; ++r) {
    int idx = r * 256 + t;           // 1024 float4 tasks
    int c = idx >> 4;
    int qq = idx & 15;
    *(float4*)&xs[c][qq * 4] = *(const float4*)(xb + (size_t)c * N_DIM + n0 + qq * 4);
  }
  __syncthreads();
  int n = t >> 2, cg = t & 3;        // 64 n x 4 c-groups of 16
  float v[16];
  #pragma unroll
  for (int cc = 0; cc < 16; ++cc) v[cc] = xs[cg * 16 + cc][n];
  double ps = 0.0;
  #pragma unroll
  for (int cc = 0; cc < 16; ++cc) ps = fma((double)v[cc], (double)v[cc], ps);
  ps += __shfl_xor(ps, 1, 64);
  ps += __shfl_xor(ps, 2, 64);       // lanes t^1,t^2 share n
  size_t row = (size_t)b * N_DIM + n0 + n;
  #pragma unroll
  for (int qq = 0; qq < 4; ++qq) {
    float4 wv; wv.x = v[qq*4]; wv.y = v[qq*4+1]; wv.z = v[qq*4+2]; wv.w = v[qq*4+3];
    *(float4*)&xT[row * C_DIM + cg * 16 + qq * 4] = wv;
  }
  if (cg == 0) nf[row] = (float)ps;
}

// ---- kernel 2: split-bf16 MFMA distance sweep, on-the-fly split ----
// grid = B*32*4 = 2048 blocks (64-row itile x j-quarter), 256 thr (4 waves).
// A-operand = J-tile (LDS 32KB, split+swizzled during staging),
// B-operand = I-frags (registers, split at load). (256,4): r7's proven
// no-spill config (r8's (256,5) forced a scratch spill at VGPR=48).
__global__ __launch_bounds__(256, 4) void topk_kernel(
    const float* __restrict__ xT, const float* __restrict__ nf,
    unsigned short* __restrict__ cand) {
  __shared__ __align__(16) unsigned short Jh[128 * 64];  // 16 KB
  __shared__ __align__(16) unsigned short Jl[128 * 64];  // 16 KB
  int bid   = blockIdx.x;
  int q     = bid & 3;               // j-quarter
  int itile = (bid >> 2) & 31;       // 32 i-tiles of 64 rows
  int b     = bid >> 7;
  int i0    = itile * 64;
  int jq0   = q * 512;
  int t = threadIdx.x;
  int w = t >> 6, lane = t & 63, quad = lane >> 4, col = lane & 15;
  int csw = col & 7;
  const float* xb  = xT + (size_t)b * N_DIM * C_DIM;
  const float* nfb = nf + b * N_DIM;

  // I-frags (B operand): direct fp32 loads + split. Element ranges match
  // the r7 swizzled-load geometry (ks*32 + quad*8).
  bf16x8 ih[2], il[2];
  {
    const float* ip = xb + (size_t)(i0 + w * 16 + col) * C_DIM + quad * 8;
    #pragma unroll
    for (int ks = 0; ks < 2; ++ks) {
      float v[8];
      *(float4*)&v[0] = *(const float4*)(ip + ks * 32);
      *(float4*)&v[4] = *(const float4*)(ip + ks * 32 + 4);
      split8(v, &ih[ks], &il[ks]);
    }
  }

  float ck[3]; int cj[3];
  ck[0] = ck[1] = ck[2] = FLT_MAX;
  cj[0] = cj[1] = cj[2] = 0;

  int a0 = col * 64 + ((quad ^ csw) * 8);        // ks=0 frag offset (shorts)
  int a1 = col * 64 + (((4 + quad) ^ csw) * 8);  // ks=1

  for (int js = 0; js < 4; ++js) {
    int j0 = jq0 + js * 128;
    __syncthreads();                 // prior frag reads done before overwrite
    {
      // stage 32 j-rows per wave: fp32 read, split, swizzled LDS store.
      // chunk c of local row r lives at c^(r&7) (same swizzle as r5-r8).
      int rr = lane >> 1, half = lane & 1;
      int lrow = w * 32 + rr;
      const float* src = xb + (size_t)(j0 + lrow) * C_DIM + half * 32;
      unsigned short* dh = &Jh[lrow * 64];
      unsigned short* dl = &Jl[lrow * 64];
      int sw = lrow & 7;
      #pragma unroll
      for (int g = 0; g < 4; ++g) {
        float v[8];
        *(float4*)&v[0] = *(const float4*)(src + g * 8);
        *(float4*)&v[4] = *(const float4*)(src + g * 8 + 4);
        bf16x8 h8, l8;
        split8(v, &h8, &l8);
        int phys = ((half * 4 + g) ^ sw) * 8;
        *(bf16x8*)(dh + phys) = h8;
        *(bf16x8*)(dl + phys) = l8;
      }
    }
    __syncthreads();

    floatx4 acc[8];
    #pragma unroll
    for (int jt = 0; jt < 8; ++jt) acc[jt] = (floatx4){0.f, 0.f, 0.f, 0.f};

    #pragma unroll
    for (int ks = 0; ks < 2; ++ks) {
      int ab = ks ? a1 : a0;
      #pragma unroll
      for (int jt = 0; jt < 8; ++jt) {
        bf16x8 jh = *(const bf16x8*)&Jh[jt * 1024 + ab];
        bf16x8 jl = *(const bf16x8*)&Jl[jt * 1024 + ab];
        acc[jt] = __builtin_amdgcn_mfma_f32_16x16x32_bf16(jl, ih[ks], acc[jt], 0, 0, 0);
        acc[jt] = __builtin_amdgcn_mfma_f32_16x16x32_bf16(jh, il[ks], acc[jt], 0, 0, 0);
        acc[jt] = __builtin_amdgcn_mfma_f32_16x16x32_bf16(jh, ih[ks], acc[jt], 0, 0, 0);
      }
    }

    // epilogue: key = nf[j] - 2*dot; j = j0 + jt*16 + quad*4 + r
    int jb = j0 + quad * 4;
    #pragma unroll
    for (int jt = 0; jt < 8; ++jt) {
      float4 nv = *(const float4*)(nfb + jb + jt * 16);
      float nfa[4] = {nv.x, nv.y, nv.z, nv.w};
      #pragma unroll
      for (int r = 0; r < 4; ++r) {
        float key = fmaf(-2.0f, acc[jt][r], nfa[r]);
        ins3(key, jb + jt * 16 + r, ck, cj);
      }
    }
  }

  // merge across the 4 quads holding the same col (= same i-row)
  #pragma unroll
  for (int m = 16; m < 64; m <<= 1) {
    float tk[3]; int tj[3];
    #pragma unroll
    for (int s = 0; s < 3; ++s) {
      tk[s] = __shfl_xor(ck[s], m, 64);
      tj[s] = __shfl_xor(cj[s], m, 64);
    }
    #pragma unroll
    for (int s = 0; s < 3; ++s) ins3(tk[s], tj[s], ck, cj);
  }
  if (quad == 0) {
    int row = b * N_DIM + i0 + w * 16 + col;
    unsigned short* cp = cand + row * 16 + q * 4;
    cp[0] = (unsigned short)cj[0];
    cp[1] = (unsigned short)cj[1];
    cp[2] = (unsigned short)cj[2];
    cp[3] = (unsigned short)cj[0];   // dup; refine masks equal u64s together
  }
}

// ---- kernel 2b: exact fp64 re-rank via order-isomorphic u64 pack ----
// Norms computed inline in fp64 from xT (exact given fp32 inputs) -> no nd
// buffer. key = |xn|^2 + |xj|^2 - 2 dot + 1 > 0, fp64 bits compare as u64;
// pack (bits & ~2047) | j -> lexicographic (dist, j). Top-3 = 3-pass masked
// min butterfly. Wave per row; lane = cand(16) x seg(4). grid = B*N/4.
__global__ __launch_bounds__(256) void refine_kernel(
    const float* __restrict__ xT, const unsigned short* __restrict__ cand,
    unsigned short* __restrict__ topk) {
  int t = threadIdx.x;
  int lane = t & 63;
  int row = blockIdx.x * 4 + (t >> 6);   // [0, B*N)
  int b = row >> 11;
  int n = row & (N_DIM - 1);
  int cid = lane >> 2;
  int seg = lane & 3;
  int j = cand[row * 16 + cid];
  const float* xn = xT + (((size_t)b * N_DIM + n) * C_DIM) + seg * 16;
  const float* xj = xT + (((size_t)b * N_DIM + j) * C_DIM) + seg * 16;
  double pd = 0.0, pn = 0.0, pj = 0.0;
  #pragma unroll
  for (int qq = 0; qq < 4; ++qq) {
    float4 a  = *(const float4*)(xn + qq * 4);
    float4 bb = *(const float4*)(xj + qq * 4);
    double ax = a.x,  ay = a.y,  az = a.z,  aw = a.w;
    double bx = bb.x, by = bb.y, bz = bb.z, bw = bb.w;
    pd = fma(ax, bx, pd); pd = fma(ay, by, pd);
    pd = fma(az, bz, pd); pd = fma(aw, bw, pd);
    pn = fma(ax, ax, pn); pn = fma(ay, ay, pn);
    pn = fma(az, az, pn); pn = fma(aw, aw, pn);
    pj = fma(bx, bx, pj); pj = fma(by, by, pj);
    pj = fma(bz, bz, pj); pj = fma(bw, bw, pj);
  }
  pd += __shfl_xor(pd, 1, 64); pd += __shfl_xor(pd, 2, 64);
  pn += __shfl_xor(pn, 1, 64); pn += __shfl_xor(pn, 2, 64);
  pj += __shfl_xor(pj, 1, 64); pj += __shfl_xor(pj, 2, 64);
  double key = (pn + pj - 2.0 * pd) + 1.0;
  unsigned long long u =
      ((unsigned long long)__double_as_longlong(key) & ~2047ull) |
      (unsigned long long)(unsigned)j;
  unsigned long long v = u;
  int jout[3];
  #pragma unroll
  for (int p = 0; p < 3; ++p) {
    unsigned long long m = v;
    #pragma unroll
    for (int msk = 4; msk < 64; msk <<= 1) {
      unsigned long long o = __shfl_xor(m, msk, 64);
      m = (o < m) ? o : m;
    }
    jout[p] = (int)(m & 2047ull);
    v = (v == m) ? ~0ull : v;        // mask winner (and all equal copies)
  }
  if (lane == 0) {
    unsigned short* tp = topk + row * K_NN;
    tp[0] = (unsigned short)jout[0];
    tp[1] = (unsigned short)jout[1];
    tp[2] = (unsigned short)jout[2];
  }
}

// ---- kernel 3: gather neighbors (coalesced via xT) + conv ----
#define NT   64
#define NPAD 68
__global__ __launch_bounds__(256) void conv_kernel(
    const float* __restrict__ xT, const float* __restrict__ Wt,
    const float* __restrict__ bias, const unsigned short* __restrict__ topk,
    float* __restrict__ out) {
  __shared__ __align__(16) float nb[C_DIM * K_NN][NPAD];  // 52224 B
  int bid = blockIdx.x;
  int b  = bid >> 5;
  int n0 = (bid & 31) * NT;
  const float* xtb = xT + (size_t)b * N_DIM * C_DIM;
  const unsigned short* tk = topk + (b * N_DIM + n0) * K_NN;
  int t = threadIdx.x;

  #pragma unroll
  for (int p = 0; p < 12; ++p) {
    int u = p * 256 + t;            // 3072 tasks: 192 rows x 16 segs
    int seg = u & 15;
    int r   = u >> 4;               // r = k*64 + n
    int k = r >> 6, n = r & 63;
    int j = tk[n * K_NN + k];
    float4 v = *(const float4*)(xtb + (size_t)j * C_DIM + seg * 4);
    nb[(seg * 4 + 0) * 3 + k][n] = v.x;
    nb[(seg * 4 + 1) * 3 + k][n] = v.y;
    nb[(seg * 4 + 2) * 3 + k][n] = v.z;
    nb[(seg * 4 + 3) * 3 + k][n] = v.w;
  }
  __syncthreads();

  int ng = t & 15, og = t >> 4;
  float acc[4][4];
  #pragma unroll
  for (int oo = 0; oo < 4; ++oo) {
    float bv = bias[(og << 2) + oo];
    #pragma unroll
    for (int nn = 0; nn < 4; ++nn) acc[oo][nn] = bv;
  }
  const float* nbp = &nb[0][0] + (ng << 2);
  const float* wtp = Wt + (og << 2);
  #pragma unroll 4
  for (int ckk = 0; ckk < C_DIM * K_NN; ++ckk) {
    float4 nv = *(const float4*)(nbp + ckk * NPAD);
    float4 wv = *(const float4*)(wtp + ckk * O_DIM);
    float na[4] = {nv.x, nv.y, nv.z, nv.w};
    float wa[4] = {wv.x, wv.y, wv.z, wv.w};
    #pragma unroll
    for (int oo = 0; oo < 4; ++oo)
      #pragma unroll
      for (int nn = 0; nn < 4; ++nn)
        acc[oo][nn] = fmaf(wa[oo], na[nn], acc[oo][nn]);
  }
  #pragma unroll
  for (int oo = 0; oo < 4; ++oo) {
    int o = (og << 2) + oo;
    float4 v; v.x = acc[oo][0]; v.y = acc[oo][1]; v.z = acc[oo][2]; v.w = acc[oo][3];
    *(float4*)&out[(size_t)(b * O_DIM + o) * N_DIM + n0 + (ng << 2)] = v;
  }
}

extern "C" void kernel_launch(void* const* d_in, const int* in_sizes, int n_in,
                              void* d_out, int out_size, void* d_ws, size_t ws_size,
                              hipStream_t stream) {
  const float* x    = (const float*)d_in[0];   // [B][C][N]
  const float* W    = (const float*)d_in[1];   // [O][C][K]
  const float* bias = (const float*)d_in[2];   // [O]
  float* out = (float*)d_out;                  // [B][O][N]
  char* ws = (char*)d_ws;
  // ws layout (bytes) -- total 9.4 MB (was 19.7; testing the ws-poison
  // tail theory):
  //   xT   fp32 [B][N][C]   @ 0        (8 MB)
  //   nf   fp32 [B*N]       @ 8388608  (128 KB)
  //   cand u16  [B*N][16]   @ 8519680  (1 MB)
  //   topk u16  [B*N][3]    @ 9568256  (192 KB)
  //   Wt   fp32 [C*K][O]    @ 9764864  (48 KB)
  float*          xT  = (float*)ws;
  float*          nfp = (float*)(ws + 8388608);
  unsigned short* cd  = (unsigned short*)(ws + 8519680);
  unsigned short* tk  = (unsigned short*)(ws + 9568256);
  float*          Wt  = (float*)(ws + 9764864);

  prep_kernel<<<512 + 48, 256, 0, stream>>>(x, xT, nfp, W, Wt);
  topk_kernel<<<B_DIM * 32 * 4, 256, 0, stream>>>(xT, nfp, cd);
  refine_kernel<<<(B_DIM * N_DIM) / 4, 256, 0, stream>>>(xT, cd, tk);
  conv_kernel<<<B_DIM * (N_DIM / NT), 256, 0, stream>>>(xT, Wt, bias, tk, out);
}

// Round 10
// 162.617 us; speedup vs baseline: 1.0453x; 1.0453x over previous
//
#include <hip/hip_runtime.h>
#include <cfloat>
#include <climits>

#define B_DIM 16
#define C_DIM 64
#define N_DIM 2048
#define O_DIM 64
#define K_NN  3

typedef __attribute__((ext_vector_type(8))) short bf16x8;
typedef __attribute__((ext_vector_type(4))) float floatx4;

__device__ __forceinline__ unsigned short f32_to_bf16_rne(float f) {
  unsigned int u = __float_as_uint(f);
  return (unsigned short)((u + 0x7fffu + ((u >> 16) & 1u)) >> 16);
}
__device__ __forceinline__ float bf16_to_f32(unsigned short h) {
  return __uint_as_float(((unsigned int)h) << 16);
}

// med3 on u32 (compiler pattern-matches to v_med3_u32)
__device__ __forceinline__ unsigned med3u(unsigned a, unsigned b, unsigned c) {
  unsigned mn = min(a, b), mx = max(a, b);
  return max(mn, min(mx, c));
}

// paired (packed-key, j) branchless top-4 insert — merge phase only
__device__ __forceinline__ void ins4p(unsigned u, int jv, unsigned* k, int* j) {
  bool c3 = u < k[3], c2 = u < k[2], c1 = u < k[1], c0 = u < k[0];
  k[3] = c2 ? k[2] : (c3 ? u  : k[3]);
  j[3] = c2 ? j[2] : (c3 ? jv : j[3]);
  k[2] = c1 ? k[1] : (c2 ? u  : k[2]);
  j[2] = c1 ? j[1] : (c2 ? jv : j[2]);
  k[1] = c0 ? k[0] : (c1 ? u  : k[1]);
  j[1] = c0 ? j[0] : (c1 ? jv : j[1]);
  k[0] = c0 ? u  : k[0];
  j[0] = c0 ? jv : j[0];
}

// ---- kernel 1: x -> xT fp32 [B][N][C], bf16 hi/lo split (chunk-swizzled:
// 16B chunk q of row n stored at q^(n&7)), fp64 norms nd, fp32 norms+512.
// Blocks >= 512 do the W transpose. ----
__global__ __launch_bounds__(256) void prep_kernel(
    const float* __restrict__ x, float* __restrict__ xT,
    unsigned short* __restrict__ xTh, unsigned short* __restrict__ xTl,
    double* __restrict__ nd, float* __restrict__ nf,
    const float* __restrict__ W, float* __restrict__ Wt) {
  int bid = blockIdx.x;
  int t = threadIdx.x;
  if (bid >= 512) {                  // W transpose: 48 blocks
    int t2 = (bid - 512) * 256 + t;  // 12288 = O * C * K
    int o  = t2 / (C_DIM * K_NN);
    int ck = t2 - o * (C_DIM * K_NN);
    Wt[ck * O_DIM + o] = W[t2];
    return;
  }
  __shared__ __align__(16) float xs[C_DIM][68];
  int b  = bid >> 5;
  int n0 = (bid & 31) * 64;
  const float* xb = x + (size_t)b * C_DIM * N_DIM;
  #pragma unroll
  for (int r = 0; r < 4; ++r) {
    int idx = r * 256 + t;           // 1024 float4 tasks
    int c = idx >> 4;
    int qq = idx & 15;
    *(float4*)&xs[c][qq * 4] = *(const float4*)(xb + (size_t)c * N_DIM + n0 + qq * 4);
  }
  __syncthreads();
  int n = t >> 2, cg = t & 3;        // 64 n x 4 c-groups of 16
  float v[16];
  #pragma unroll
  for (int cc = 0; cc < 16; ++cc) v[cc] = xs[cg * 16 + cc][n];
  double ps = 0.0;
  #pragma unroll
  for (int cc = 0; cc < 16; ++cc) ps = fma((double)v[cc], (double)v[cc], ps);
  ps += __shfl_xor(ps, 1, 64);
  ps += __shfl_xor(ps, 2, 64);       // lanes t^1,t^2 share n
  size_t row = (size_t)b * N_DIM + n0 + n;
  #pragma unroll
  for (int qq = 0; qq < 4; ++qq) {
    float4 wv; wv.x = v[qq*4]; wv.y = v[qq*4+1]; wv.z = v[qq*4+2]; wv.w = v[qq*4+3];
    *(float4*)&xT[row * C_DIM + cg * 16 + qq * 4] = wv;
  }
  unsigned short hh[16], ll[16];
  #pragma unroll
  for (int cc = 0; cc < 16; ++cc) {
    hh[cc] = f32_to_bf16_rne(v[cc]);
    ll[cc] = f32_to_bf16_rne(v[cc] - bf16_to_f32(hh[cc]));
  }
  #pragma unroll
  for (int e = 0; e < 2; ++e) {
    int phys = (2 * cg + e) ^ (n & 7);
    unsigned int hp[4], lp[4];
    #pragma unroll
    for (int xk = 0; xk < 4; ++xk) {
      hp[xk] = (unsigned)hh[e*8 + 2*xk] | ((unsigned)hh[e*8 + 2*xk + 1] << 16);
      lp[xk] = (unsigned)ll[e*8 + 2*xk] | ((unsigned)ll[e*8 + 2*xk + 1] << 16);
    }
    ((uint4*)xTh)[row * 8 + phys] = *(uint4*)hp;
    ((uint4*)xTl)[row * 8 + phys] = *(uint4*)lp;
  }
  if (cg == 0) {
    nd[row] = ps;
    nf[row] = (float)ps + 512.0f;    // pre-biased: key' = fma(-2,acc,nf) > 0
  }
}

// ---- kernel 2: split-bf16 MFMA distance sweep, packed-u32 top-4 ----
// 2 dispatches (batch halves, for profiler visibility). grid = 8*32*4 = 1024
// blocks each (64-row itile x j-quarter), 256 thr. A = J-tile (LDS 32KB),
// B = I-frags (regs, r7 precomputed-split staging: pure 16B copies).
// Epilogue: key+512 > 0 -> float bits order-isomorphic as u32; steal 7 low
// bits for stream-local (js,jt,r) id; sorted top-4 via min+med3 (4 ops/key).
// Exact fp64 refine re-ranks the 16-candidate pool, so 4e-3 quantization
// only needs to preserve candidate MEMBERSHIP (gaps ~0.3 >> 4e-3).
__global__ __launch_bounds__(256, 4) void topk_kernel(
    const unsigned short* __restrict__ xTh, const unsigned short* __restrict__ xTl,
    const float* __restrict__ nf, unsigned short* __restrict__ cand, int b_base) {
  __shared__ __align__(16) unsigned short Jh[128 * 64];  // 16 KB
  __shared__ __align__(16) unsigned short Jl[128 * 64];  // 16 KB
  int bid   = blockIdx.x;
  int q     = bid & 3;               // j-quarter
  int itile = (bid >> 2) & 31;       // 32 i-tiles of 64 rows
  int b     = b_base + (bid >> 7);
  int i0    = itile * 64;
  int jq0   = q * 512;
  int t = threadIdx.x;
  int w = t >> 6, lane = t & 63, quad = lane >> 4, col = lane & 15;
  int csw = col & 7;
  const unsigned short* xh = xTh + (size_t)b * N_DIM * 64;
  const unsigned short* xl = xTl + (size_t)b * N_DIM * 64;
  const float* nfb = nf + b * N_DIM;

  // I-frags (B operand) once from global. row&7 == col&7 == csw.
  bf16x8 ih[2], il[2];
  #pragma unroll
  for (int ks = 0; ks < 2; ++ks) {
    size_t row = i0 + w * 16 + col;
    int phys = (ks * 4 + quad) ^ csw;
    ih[ks] = *(const bf16x8*)(xh + row * 64 + phys * 8);
    il[ks] = *(const bf16x8*)(xl + row * 64 + phys * 8);
  }

  unsigned ck[4];
  ck[0] = ck[1] = ck[2] = ck[3] = 0xFFFFFFFFu;

  int a0 = col * 64 + ((quad ^ csw) * 8);        // ks=0 frag offset (shorts)
  int a1 = col * 64 + (((4 + quad) ^ csw) * 8);  // ks=1

  for (int js = 0; js < 4; ++js) {
    int j0 = jq0 + js * 128;
    __syncthreads();                 // prior frag reads done before overwrite
    {
      // stage 32 j-rows per wave: pure 16B copies, layout verbatim
      const unsigned short* sh = xh + (size_t)(j0 + w * 32) * 64;
      const unsigned short* sl = xl + (size_t)(j0 + w * 32) * 64;
      unsigned short* dh = &Jh[w * 32 * 64];
      unsigned short* dl = &Jl[w * 32 * 64];
      int off = lane * 8;
      #pragma unroll
      for (int k2 = 0; k2 < 4; ++k2) {
        *(uint4*)(dh + k2 * 512 + off) = *(const uint4*)(sh + k2 * 512 + off);
        *(uint4*)(dl + k2 * 512 + off) = *(const uint4*)(sl + k2 * 512 + off);
      }
    }
    __syncthreads();

    floatx4 acc[8];
    #pragma unroll
    for (int jt = 0; jt < 8; ++jt) acc[jt] = (floatx4){0.f, 0.f, 0.f, 0.f};

    #pragma unroll
    for (int ks = 0; ks < 2; ++ks) {
      int ab = ks ? a1 : a0;
      #pragma unroll
      for (int jt = 0; jt < 8; ++jt) {
        bf16x8 jh = *(const bf16x8*)&Jh[jt * 1024 + ab];
        bf16x8 jl = *(const bf16x8*)&Jl[jt * 1024 + ab];
        acc[jt] = __builtin_amdgcn_mfma_f32_16x16x32_bf16(jl, ih[ks], acc[jt], 0, 0, 0);
        acc[jt] = __builtin_amdgcn_mfma_f32_16x16x32_bf16(jh, il[ks], acc[jt], 0, 0, 0);
        acc[jt] = __builtin_amdgcn_mfma_f32_16x16x32_bf16(jh, ih[ks], acc[jt], 0, 0, 0);
      }
    }

    // epilogue: key' = nf512[j] - 2*dot (> 0 by construction);
    // pack (bits & ~127) | (js<<5 | jt*4+r); min+med3 sorted top-4.
    unsigned locb = (unsigned)(js << 5);
    int jb = j0 + quad * 4;
    #pragma unroll
    for (int jt = 0; jt < 8; ++jt) {
      float4 nv = *(const float4*)(nfb + jb + jt * 16);
      float nfa[4] = {nv.x, nv.y, nv.z, nv.w};
      #pragma unroll
      for (int r = 0; r < 4; ++r) {
        float key = fmaf(-2.0f, acc[jt][r], nfa[r]);
        unsigned u = (__float_as_uint(key) & 0xFFFFFF80u) | locb |
                     (unsigned)(jt * 4 + r);
        unsigned m0 = min(ck[0], u);
        unsigned m1 = med3u(ck[0], u, ck[1]);
        unsigned m2 = med3u(ck[1], u, ck[2]);
        unsigned m3 = med3u(ck[2], u, ck[3]);
        ck[0] = m0; ck[1] = m1; ck[2] = m2; ck[3] = m3;
      }
    }
  }

  // decode stream-local ids -> global j (quad known only pre-merge)
  int cj[4];
  #pragma unroll
  for (int s = 0; s < 4; ++s) {
    unsigned loc = ck[s] & 127u;
    cj[s] = jq0 + (int)((loc >> 5) << 7) + (int)(((loc >> 2) & 7u) << 4) +
            (quad << 2) + (int)(loc & 3u);
  }
  // paired merge across the 4 quads holding the same col (= same i-row)
  #pragma unroll
  for (int m = 16; m < 64; m <<= 1) {
    unsigned tu[4]; int tj[4];
    #pragma unroll
    for (int s = 0; s < 4; ++s) {
      tu[s] = __shfl_xor(ck[s], m, 64);
      tj[s] = __shfl_xor(cj[s], m, 64);
    }
    #pragma unroll
    for (int s = 0; s < 4; ++s) ins4p(tu[s], tj[s], ck, cj);
  }
  if (quad == 0) {
    int row = b * N_DIM + i0 + w * 16 + col;
    unsigned short* cp = cand + row * 16 + q * 4;
    cp[0] = (unsigned short)cj[0];
    cp[1] = (unsigned short)cj[1];
    cp[2] = (unsigned short)cj[2];
    cp[3] = (unsigned short)cj[3];
  }
}

// ---- kernel 2b: exact fp64 re-rank, dot-chain only (norms from nd) ----
// key = nd[j] - 2*pd + 512 > 0; fp64 bits compare as u64; pack
// (bits & ~2047) | j -> lexicographic (dist, j). Top-3 = 3-pass masked min
// butterfly. Wave per row; lane = cand(16) x seg(4). grid = B*N/4.
__global__ __launch_bounds__(256) void refine_kernel(
    const float* __restrict__ xT, const double* __restrict__ nd,
    const unsigned short* __restrict__ cand, unsigned short* __restrict__ topk) {
  int t = threadIdx.x;
  int lane = t & 63;
  int row = blockIdx.x * 4 + (t >> 6);   // [0, B*N)
  int b = row >> 11;
  int n = row & (N_DIM - 1);
  int cid = lane >> 2;
  int seg = lane & 3;
  int j = cand[row * 16 + cid];
  const float* xn = xT + (((size_t)b * N_DIM + n) * C_DIM) + seg * 16;
  const float* xj = xT + (((size_t)b * N_DIM + j) * C_DIM) + seg * 16;
  double pd = 0.0;
  #pragma unroll
  for (int qq = 0; qq < 4; ++qq) {
    float4 a  = *(const float4*)(xn + qq * 4);
    float4 bb = *(const float4*)(xj + qq * 4);
    pd = fma((double)a.x, (double)bb.x, pd);
    pd = fma((double)a.y, (double)bb.y, pd);
    pd = fma((double)a.z, (double)bb.z, pd);
    pd = fma((double)a.w, (double)bb.w, pd);
  }
  pd += __shfl_xor(pd, 1, 64);       // reduce over seg
  pd += __shfl_xor(pd, 2, 64);
  double key = fma(-2.0, pd, nd[b * N_DIM + j] + 512.0);  // > 0 always
  unsigned long long u =
      ((unsigned long long)__double_as_longlong(key) & ~2047ull) |
      (unsigned long long)(unsigned)j;
  unsigned long long v = u;
  int jout[3];
  #pragma unroll
  for (int p = 0; p < 3; ++p) {
    unsigned long long m = v;
    #pragma unroll
    for (int msk = 4; msk < 64; msk <<= 1) {
      unsigned long long o = __shfl_xor(m, msk, 64);
      m = (o < m) ? o : m;
    }
    jout[p] = (int)(m & 2047ull);
    v = (v == m) ? ~0ull : v;        // mask winner (and all equal copies)
  }
  if (lane == 0) {
    unsigned short* tp = topk + row * K_NN;
    tp[0] = (unsigned short)jout[0];
    tp[1] = (unsigned short)jout[1];
    tp[2] = (unsigned short)jout[2];
  }
}

// ---- kernel 3: gather neighbors (coalesced via xT) + conv ----
#define NT   64
#define NPAD 68
__global__ __launch_bounds__(256) void conv_kernel(
    const float* __restrict__ xT, const float* __restrict__ Wt,
    const float* __restrict__ bias, const unsigned short* __restrict__ topk,
    float* __restrict__ out) {
  __shared__ __align__(16) float nb[C_DIM * K_NN][NPAD];  // 52224 B
  int bid = blockIdx.x;
  int b  = bid >> 5;
  int n0 = (bid & 31) * NT;
  const float* xtb = xT + (size_t)b * N_DIM * C_DIM;
  const unsigned short* tk = topk + (b * N_DIM + n0) * K_NN;
  int t = threadIdx.x;

  #pragma unroll
  for (int p = 0; p < 12; ++p) {
    int u = p * 256 + t;            // 3072 tasks: 192 rows x 16 segs
    int seg = u & 15;
    int r   = u >> 4;               // r = k*64 + n
    int k = r >> 6, n = r & 63;
    int j = tk[n * K_NN + k];
    float4 v = *(const float4*)(xtb + (size_t)j * C_DIM + seg * 4);
    nb[(seg * 4 + 0) * 3 + k][n] = v.x;
    nb[(seg * 4 + 1) * 3 + k][n] = v.y;
    nb[(seg * 4 + 2) * 3 + k][n] = v.z;
    nb[(seg * 4 + 3) * 3 + k][n] = v.w;
  }
  __syncthreads();

  int ng = t & 15, og = t >> 4;
  float acc[4][4];
  #pragma unroll
  for (int oo = 0; oo < 4; ++oo) {
    float bv = bias[(og << 2) + oo];
    #pragma unroll
    for (int nn = 0; nn < 4; ++nn) acc[oo][nn] = bv;
  }
  const float* nbp = &nb[0][0] + (ng << 2);
  const float* wtp = Wt + (og << 2);
  #pragma unroll 4
  for (int ckk = 0; ckk < C_DIM * K_NN; ++ckk) {
    float4 nv = *(const float4*)(nbp + ckk * NPAD);
    float4 wv = *(const float4*)(wtp + ckk * O_DIM);
    float na[4] = {nv.x, nv.y, nv.z, nv.w};
    float wa[4] = {wv.x, wv.y, wv.z, wv.w};
    #pragma unroll
    for (int oo = 0; oo < 4; ++oo)
      #pragma unroll
      for (int nn = 0; nn < 4; ++nn)
        acc[oo][nn] = fmaf(wa[oo], na[nn], acc[oo][nn]);
  }
  #pragma unroll
  for (int oo = 0; oo < 4; ++oo) {
    int o = (og << 2) + oo;
    float4 v; v.x = acc[oo][0]; v.y = acc[oo][1]; v.z = acc[oo][2]; v.w = acc[oo][3];
    *(float4*)&out[(size_t)(b * O_DIM + o) * N_DIM + n0 + (ng << 2)] = v;
  }
}

extern "C" void kernel_launch(void* const* d_in, const int* in_sizes, int n_in,
                              void* d_out, int out_size, void* d_ws, size_t ws_size,
                              hipStream_t stream) {
  const float* x    = (const float*)d_in[0];   // [B][C][N]
  const float* W    = (const float*)d_in[1];   // [O][C][K]
  const float* bias = (const float*)d_in[2];   // [O]
  float* out = (float*)d_out;                  // [B][O][N]
  char* ws = (char*)d_ws;
  // ws layout (bytes):
  //   xT   fp32 [B][N][C]           @ 0         (8 MB)
  //   xTh  bf16 [B][N][C] swizzled  @ 8388608   (4 MB)
  //   xTl  bf16 [B][N][C] swizzled  @ 12582912  (4 MB)
  //   nd   fp64 [B*N]               @ 16777216  (256 KB)
  //   nf   fp32 [B*N] (norm+512)    @ 17039360  (128 KB)
  //   cand u16  [B*N][16]           @ 17170432  (1 MB)
  //   topk u16  [B*N][3]            @ 18219008  (192 KB)
  //   Wt   fp32 [C*K][O]            @ 18415616  (48 KB)
  float*          xT  = (float*)ws;
  unsigned short* xTh = (unsigned short*)(ws + 8388608);
  unsigned short* xTl = (unsigned short*)(ws + 12582912);
  double*         nd  = (double*)(ws + 16777216);
  float*          nfp = (float*)(ws + 17039360);
  unsigned short* cd  = (unsigned short*)(ws + 17170432);
  unsigned short* tk  = (unsigned short*)(ws + 18219008);
  float*          Wt  = (float*)(ws + 18415616);

  prep_kernel<<<512 + 48, 256, 0, stream>>>(x, xT, xTh, xTl, nd, nfp, W, Wt);
  topk_kernel<<<8 * 32 * 4, 256, 0, stream>>>(xTh, xTl, nfp, cd, 0);
  topk_kernel<<<8 * 32 * 4, 256, 0, stream>>>(xTh, xTl, nfp, cd, 8);
  refine_kernel<<<(B_DIM * N_DIM) / 4, 256, 0, stream>>>(xT, nd, cd, tk);
  conv_kernel<<<B_DIM * (N_DIM / NT), 256, 0, stream>>>(xT, Wt, bias, tk, out);
}

// Round 12
// 162.096 us; speedup vs baseline: 1.0487x; 1.0032x over previous
//
#include <hip/hip_runtime.h>
#include <cfloat>
#include <climits>

#define B_DIM 16
#define C_DIM 64
#define N_DIM 2048
#define O_DIM 64
#define K_NN  3

typedef __attribute__((ext_vector_type(8))) short bf16x8;
typedef __attribute__((ext_vector_type(4))) float floatx4;

__device__ __forceinline__ unsigned short f32_to_bf16_rne(float f) {
  unsigned int u = __float_as_uint(f);
  return (unsigned short)((u + 0x7fffu + ((u >> 16) & 1u)) >> 16);
}
__device__ __forceinline__ float bf16_to_f32(unsigned short h) {
  return __uint_as_float(((unsigned int)h) << 16);
}

// med3 on u32 (compiler pattern-matches to v_med3_u32)
__device__ __forceinline__ unsigned med3u(unsigned a, unsigned b, unsigned c) {
  unsigned mn = min(a, b), mx = max(a, b);
  return max(mn, min(mx, c));
}

// paired (packed-key, j) branchless top-4 insert — merge phase only
__device__ __forceinline__ void ins4p(unsigned u, int jv, unsigned* k, int* j) {
  bool c3 = u < k[3], c2 = u < k[2], c1 = u < k[1], c0 = u < k[0];
  k[3] = c2 ? k[2] : (c3 ? u  : k[3]);
  j[3] = c2 ? j[2] : (c3 ? jv : j[3]);
  k[2] = c1 ? k[1] : (c2 ? u  : k[2]);
  j[2] = c1 ? j[1] : (c2 ? jv : j[2]);
  k[1] = c0 ? k[0] : (c1 ? u  : k[1]);
  j[1] = c0 ? j[0] : (c1 ? jv : j[1]);
  k[0] = c0 ? u  : k[0];
  j[0] = c0 ? jv : j[0];
}

// ---- kernel 1: x -> xT fp32 [B][N][C], bf16 hi/lo split (chunk-swizzled:
// 16B chunk q of row n stored at q^(n&7)), fp64 norms nd, fp32 norms+512.
// Blocks >= 512 do the W transpose. ----
__global__ __launch_bounds__(256) void prep_kernel(
    const float* __restrict__ x, float* __restrict__ xT,
    unsigned short* __restrict__ xTh, unsigned short* __restrict__ xTl,
    double* __restrict__ nd, float* __restrict__ nf,
    const float* __restrict__ W, float* __restrict__ Wt) {
  int bid = blockIdx.x;
  int t = threadIdx.x;
  if (bid >= 512) {                  // W transpose: 48 blocks
    int t2 = (bid - 512) * 256 + t;  // 12288 = O * C * K
    int o  = t2 / (C_DIM * K_NN);
    int ck = t2 - o * (C_DIM * K_NN);
    Wt[ck * O_DIM + o] = W[t2];
    return;
  }
  __shared__ __align__(16) float xs[C_DIM][68];
  int b  = bid >> 5;
  int n0 = (bid & 31) * 64;
  const float* xb = x + (size_t)b * C_DIM * N_DIM;
  #pragma unroll
  for (int r = 0; r < 4; ++r) {
    int idx = r * 256 + t;           // 1024 float4 tasks
    int c = idx >> 4;
    int qq = idx & 15;
    *(float4*)&xs[c][qq * 4] = *(const float4*)(xb + (size_t)c * N_DIM + n0 + qq * 4);
  }
  __syncthreads();
  int n = t >> 2, cg = t & 3;        // 64 n x 4 c-groups of 16
  float v[16];
  #pragma unroll
  for (int cc = 0; cc < 16; ++cc) v[cc] = xs[cg * 16 + cc][n];
  double ps = 0.0;
  #pragma unroll
  for (int cc = 0; cc < 16; ++cc) ps = fma((double)v[cc], (double)v[cc], ps);
  ps += __shfl_xor(ps, 1, 64);
  ps += __shfl_xor(ps, 2, 64);       // lanes t^1,t^2 share n
  size_t row = (size_t)b * N_DIM + n0 + n;
  #pragma unroll
  for (int qq = 0; qq < 4; ++qq) {
    float4 wv; wv.x = v[qq*4]; wv.y = v[qq*4+1]; wv.z = v[qq*4+2]; wv.w = v[qq*4+3];
    *(float4*)&xT[row * C_DIM + cg * 16 + qq * 4] = wv;
  }
  unsigned short hh[16], ll[16];
  #pragma unroll
  for (int cc = 0; cc < 16; ++cc) {
    hh[cc] = f32_to_bf16_rne(v[cc]);
    ll[cc] = f32_to_bf16_rne(v[cc] - bf16_to_f32(hh[cc]));
  }
  #pragma unroll
  for (int e = 0; e < 2; ++e) {
    int phys = (2 * cg + e) ^ (n & 7);
    unsigned int hp[4], lp[4];
    #pragma unroll
    for (int xk = 0; xk < 4; ++xk) {
      hp[xk] = (unsigned)hh[e*8 + 2*xk] | ((unsigned)hh[e*8 + 2*xk + 1] << 16);
      lp[xk] = (unsigned)ll[e*8 + 2*xk] | ((unsigned)ll[e*8 + 2*xk + 1] << 16);
    }
    ((uint4*)xTh)[row * 8 + phys] = *(uint4*)hp;
    ((uint4*)xTl)[row * 8 + phys] = *(uint4*)lp;
  }
  if (cg == 0) {
    nd[row] = ps;
    nf[row] = (float)ps + 512.0f;    // pre-biased: key' = fma(-2,acc,nf) > 0
  }
}

// ---- kernel 2: split-bf16 MFMA distance sweep, packed-u32 top-4 ----
// grid = B*32*4 = 2048 blocks (64-row itile x j-quarter), 256 thr.
// A = J-tile (LDS 32KB), B = I-frags (regs, precomputed-split staging).
// Epilogue: key+512 > 0 -> float bits order-isomorphic as u32; steal 7 low
// bits for stream-local (js,jt,r) id; sorted TOP-4 via min+3 med3.
// Top-4 (not 3!) per quad stream: the 7-bit quantization (step ~7.8e-3)
// can invert near-ties; with top-4 a true top-3 member survives unless TWO
// inversions stack (r10 passed bitwise); with top-3 one inversion evicts
// it (r11 failed, absmax 0.92). Exact fp64 refine re-ranks the pool.
__global__ __launch_bounds__(256, 4) void topk_kernel(
    const unsigned short* __restrict__ xTh, const unsigned short* __restrict__ xTl,
    const float* __restrict__ nf, unsigned short* __restrict__ cand) {
  __shared__ __align__(16) unsigned short Jh[128 * 64];  // 16 KB
  __shared__ __align__(16) unsigned short Jl[128 * 64];  // 16 KB
  int bid   = blockIdx.x;
  int q     = bid & 3;               // j-quarter
  int itile = (bid >> 2) & 31;       // 32 i-tiles of 64 rows
  int b     = bid >> 7;
  int i0    = itile * 64;
  int jq0   = q * 512;
  int t = threadIdx.x;
  int w = t >> 6, lane = t & 63, quad = lane >> 4, col = lane & 15;
  int csw = col & 7;
  const unsigned short* xh = xTh + (size_t)b * N_DIM * 64;
  const unsigned short* xl = xTl + (size_t)b * N_DIM * 64;
  const float* nfb = nf + b * N_DIM;

  // I-frags (B operand) once from global. row&7 == col&7 == csw.
  bf16x8 ih[2], il[2];
  #pragma unroll
  for (int ks = 0; ks < 2; ++ks) {
    size_t row = i0 + w * 16 + col;
    int phys = (ks * 4 + quad) ^ csw;
    ih[ks] = *(const bf16x8*)(xh + row * 64 + phys * 8);
    il[ks] = *(const bf16x8*)(xl + row * 64 + phys * 8);
  }

  unsigned ck[4];
  ck[0] = ck[1] = ck[2] = ck[3] = 0xFFFFFFFFu;

  int a0 = col * 64 + ((quad ^ csw) * 8);        // ks=0 frag offset (shorts)
  int a1 = col * 64 + (((4 + quad) ^ csw) * 8);  // ks=1

  for (int js = 0; js < 4; ++js) {
    int j0 = jq0 + js * 128;
    __syncthreads();                 // prior frag reads done before overwrite
    {
      // stage 32 j-rows per wave: pure 16B copies, layout verbatim
      const unsigned short* sh = xh + (size_t)(j0 + w * 32) * 64;
      const unsigned short* sl = xl + (size_t)(j0 + w * 32) * 64;
      unsigned short* dh = &Jh[w * 32 * 64];
      unsigned short* dl = &Jl[w * 32 * 64];
      int off = lane * 8;
      #pragma unroll
      for (int k2 = 0; k2 < 4; ++k2) {
        *(uint4*)(dh + k2 * 512 + off) = *(const uint4*)(sh + k2 * 512 + off);
        *(uint4*)(dl + k2 * 512 + off) = *(const uint4*)(sl + k2 * 512 + off);
      }
    }
    __syncthreads();

    floatx4 acc[8];
    #pragma unroll
    for (int jt = 0; jt < 8; ++jt) acc[jt] = (floatx4){0.f, 0.f, 0.f, 0.f};

    #pragma unroll
    for (int ks = 0; ks < 2; ++ks) {
      int ab = ks ? a1 : a0;
      #pragma unroll
      for (int jt = 0; jt < 8; ++jt) {
        bf16x8 jh = *(const bf16x8*)&Jh[jt * 1024 + ab];
        bf16x8 jl = *(const bf16x8*)&Jl[jt * 1024 + ab];
        acc[jt] = __builtin_amdgcn_mfma_f32_16x16x32_bf16(jl, ih[ks], acc[jt], 0, 0, 0);
        acc[jt] = __builtin_amdgcn_mfma_f32_16x16x32_bf16(jh, il[ks], acc[jt], 0, 0, 0);
        acc[jt] = __builtin_amdgcn_mfma_f32_16x16x32_bf16(jh, ih[ks], acc[jt], 0, 0, 0);
      }
    }

    // epilogue: key' = nf512[j] - 2*dot (> 0); pack (bits & ~127) |
    // (js<<5 | jt*4+r); sorted top-4 via min + 3 med3 (r10 verbatim).
    unsigned locb = (unsigned)(js << 5);
    int jb = j0 + quad * 4;
    #pragma unroll
    for (int jt = 0; jt < 8; ++jt) {
      float4 nv = *(const float4*)(nfb + jb + jt * 16);
      float nfa[4] = {nv.x, nv.y, nv.z, nv.w};
      #pragma unroll
      for (int r = 0; r < 4; ++r) {
        float key = fmaf(-2.0f, acc[jt][r], nfa[r]);
        unsigned u = (__float_as_uint(key) & 0xFFFFFF80u) | locb |
                     (unsigned)(jt * 4 + r);
        unsigned m0 = min(ck[0], u);
        unsigned m1 = med3u(ck[0], u, ck[1]);
        unsigned m2 = med3u(ck[1], u, ck[2]);
        unsigned m3 = med3u(ck[2], u, ck[3]);
        ck[0] = m0; ck[1] = m1; ck[2] = m2; ck[3] = m3;
      }
    }
  }

  // decode stream-local ids -> global j (quad known only pre-merge)
  int cj[4];
  #pragma unroll
  for (int s = 0; s < 4; ++s) {
    unsigned loc = ck[s] & 127u;
    cj[s] = jq0 + (int)((loc >> 5) << 7) + (int)(((loc >> 2) & 7u) << 4) +
            (quad << 2) + (int)(loc & 3u);
  }
  // paired merge across the 4 quads holding the same col (= same i-row)
  #pragma unroll
  for (int m = 16; m < 64; m <<= 1) {
    unsigned tu[4]; int tj[4];
    #pragma unroll
    for (int s = 0; s < 4; ++s) {
      tu[s] = __shfl_xor(ck[s], m, 64);
      tj[s] = __shfl_xor(cj[s], m, 64);
    }
    #pragma unroll
    for (int s = 0; s < 4; ++s) ins4p(tu[s], tj[s], ck, cj);
  }
  if (quad == 0) {
    int row = b * N_DIM + i0 + w * 16 + col;
    unsigned short* cp = cand + row * 16 + q * 4;
    cp[0] = (unsigned short)cj[0];
    cp[1] = (unsigned short)cj[1];
    cp[2] = (unsigned short)cj[2];
    cp[3] = (unsigned short)cj[3];
  }
}

// ---- kernel 3: fused exact-fp64 refine + gather + conv ----
// Phase 1 (refine): wave w re-ranks rows n0+w*16 .. +15 from the 16-cand
// pool (lane = cand x seg; coalesced loads; u64 order-isomorphic pack with
// j in low 11 bits; 3-pass masked min butterfly) -> top-3 into LDS.
// Phase 2: gather neighbors via xT + per-window conv (unchanged math).
#define NT   64
#define NPAD 68
__global__ __launch_bounds__(256) void conv_kernel(
    const float* __restrict__ xT, const double* __restrict__ nd,
    const unsigned short* __restrict__ cand,
    const float* __restrict__ Wt, const float* __restrict__ bias,
    float* __restrict__ out) {
  __shared__ __align__(16) float nb[C_DIM * K_NN][NPAD];  // 52224 B
  __shared__ unsigned short tks[NT][4];
  int bid = blockIdx.x;
  int b  = bid >> 5;
  int n0 = (bid & 31) * NT;
  const float* xtb = xT + (size_t)b * N_DIM * C_DIM;
  int t = threadIdx.x;
  int w = t >> 6, lane = t & 63;
  int cid = lane >> 2, seg = lane & 3;

  // ---- refine phase: 16 rows per wave ----
  for (int it = 0; it < 16; ++it) {
    int nn = w * 16 + it;
    int row = b * N_DIM + n0 + nn;
    int j = cand[row * 16 + cid];
    const float* xn = xtb + ((size_t)(n0 + nn) * C_DIM) + seg * 16;
    const float* xj = xtb + ((size_t)j * C_DIM) + seg * 16;
    double pd = 0.0;
    #pragma unroll
    for (int qq = 0; qq < 4; ++qq) {
      float4 a  = *(const float4*)(xn + qq * 4);
      float4 bb = *(const float4*)(xj + qq * 4);
      pd = fma((double)a.x, (double)bb.x, pd);
      pd = fma((double)a.y, (double)bb.y, pd);
      pd = fma((double)a.z, (double)bb.z, pd);
      pd = fma((double)a.w, (double)bb.w, pd);
    }
    pd += __shfl_xor(pd, 1, 64);     // reduce over seg
    pd += __shfl_xor(pd, 2, 64);
    double key = fma(-2.0, pd, nd[b * N_DIM + j] + 512.0);  // > 0 always
    unsigned long long u =
        ((unsigned long long)__double_as_longlong(key) & ~2047ull) |
        (unsigned long long)(unsigned)j;
    unsigned long long v = u;
    #pragma unroll
    for (int p = 0; p < 3; ++p) {
      unsigned long long m = v;
      #pragma unroll
      for (int msk = 4; msk < 64; msk <<= 1) {
        unsigned long long o = __shfl_xor(m, msk, 64);
        m = (o < m) ? o : m;
      }
      if (lane == 0) tks[nn][p] = (unsigned short)(m & 2047ull);
      v = (v == m) ? ~0ull : v;      // mask winner (and all equal copies)
    }
  }
  __syncthreads();

  // ---- gather phase ----
  #pragma unroll
  for (int p = 0; p < 12; ++p) {
    int u = p * 256 + t;            // 3072 tasks: 192 rows x 16 segs
    int sg = u & 15;
    int r  = u >> 4;                // r = k*64 + n
    int k = r >> 6, n = r & 63;
    int j = tks[n][k];
    float4 v = *(const float4*)(xtb + (size_t)j * C_DIM + sg * 4);
    nb[(sg * 4 + 0) * 3 + k][n] = v.x;
    nb[(sg * 4 + 1) * 3 + k][n] = v.y;
    nb[(sg * 4 + 2) * 3 + k][n] = v.z;
    nb[(sg * 4 + 3) * 3 + k][n] = v.w;
  }
  __syncthreads();

  // ---- conv phase ----
  int ng = t & 15, og = t >> 4;
  float acc[4][4];
  #pragma unroll
  for (int oo = 0; oo < 4; ++oo) {
    float bv = bias[(og << 2) + oo];
    #pragma unroll
    for (int nn2 = 0; nn2 < 4; ++nn2) acc[oo][nn2] = bv;
  }
  const float* nbp = &nb[0][0] + (ng << 2);
  const float* wtp = Wt + (og << 2);
  #pragma unroll 4
  for (int ckk = 0; ckk < C_DIM * K_NN; ++ckk) {
    float4 nv = *(const float4*)(nbp + ckk * NPAD);
    float4 wv = *(const float4*)(wtp + ckk * O_DIM);
    float na[4] = {nv.x, nv.y, nv.z, nv.w};
    float wa[4] = {wv.x, wv.y, wv.z, wv.w};
    #pragma unroll
    for (int oo = 0; oo < 4; ++oo)
      #pragma unroll
      for (int nn2 = 0; nn2 < 4; ++nn2)
        acc[oo][nn2] = fmaf(wa[oo], na[nn2], acc[oo][nn2]);
  }
  #pragma unroll
  for (int oo = 0; oo < 4; ++oo) {
    int o = (og << 2) + oo;
    float4 v; v.x = acc[oo][0]; v.y = acc[oo][1]; v.z = acc[oo][2]; v.w = acc[oo][3];
    *(float4*)&out[(size_t)(b * O_DIM + o) * N_DIM + n0 + (ng << 2)] = v;
  }
}

extern "C" void kernel_launch(void* const* d_in, const int* in_sizes, int n_in,
                              void* d_out, int out_size, void* d_ws, size_t ws_size,
                              hipStream_t stream) {
  const float* x    = (const float*)d_in[0];   // [B][C][N]
  const float* W    = (const float*)d_in[1];   // [O][C][K]
  const float* bias = (const float*)d_in[2];   // [O]
  float* out = (float*)d_out;                  // [B][O][N]
  char* ws = (char*)d_ws;
  // ws layout (bytes):
  //   xT   fp32 [B][N][C]           @ 0         (8 MB)
  //   xTh  bf16 [B][N][C] swizzled  @ 8388608   (4 MB)
  //   xTl  bf16 [B][N][C] swizzled  @ 12582912  (4 MB)
  //   nd   fp64 [B*N]               @ 16777216  (256 KB)
  //   nf   fp32 [B*N] (norm+512)    @ 17039360  (128 KB)
  //   cand u16  [B*N][16]           @ 17170432  (1 MB)
  //   Wt   fp32 [C*K][O]            @ 18219008  (48 KB)
  float*          xT  = (float*)ws;
  unsigned short* xTh = (unsigned short*)(ws + 8388608);
  unsigned short* xTl = (unsigned short*)(ws + 12582912);
  double*         nd  = (double*)(ws + 16777216);
  float*          nfp = (float*)(ws + 17039360);
  unsigned short* cd  = (unsigned short*)(ws + 17170432);
  float*          Wt  = (float*)(ws + 18219008);

  prep_kernel<<<512 + 48, 256, 0, stream>>>(x, xT, xTh, xTl, nd, nfp, W, Wt);
  topk_kernel<<<B_DIM * 32 * 4, 256, 0, stream>>>(xTh, xTl, nfp, cd);
  conv_kernel<<<B_DIM * (N_DIM / NT), 256, 0, stream>>>(xT, nd, cd, Wt, bias, out);
}